// Round 6
// baseline (21045.770 us; speedup 1.0000x reference)
//
#include <hip/hip_runtime.h>
#include <math.h>

#define BB 8
#define TT 4096
#define DD 512
constexpr float LRF = 0.01f;

// ---------------- workspace layout (floats) ----------------
// A  : [4096][512]        mean of x over batch
// CU : [4096][512]        c_s * u_s
// G  : [16][256][256]     per-superchunk Gram of A
// P  : [256][512]         A_sc - A_sc @ W(p)^T   (reused per superchunk)
// W  : [512][512]         running W_base + W_c
// WS : [16][512][512]     W snapshots at t = 256*p
// S  : [16][2048][256]    attention scores
#define OFF_A  0
#define OFF_CU 2097152
#define OFF_G  4194304
#define OFF_P  5242880
#define OFF_W  5406720
#define OFF_WS 5668864
#define OFF_S  9863168

__global__ void tm_mean(const float* __restrict__ x, float* __restrict__ a) {
    int idx = blockIdx.x * 256 + threadIdx.x;   // t*D + d
    float s = 0.f;
#pragma unroll
    for (int b = 0; b < BB; ++b) s += x[b * (TT * DD) + idx];
    a[idx] = s * 0.125f;
}

__global__ void tm_init(const float* __restrict__ wb, const float* __restrict__ wc,
                        float* __restrict__ W, float* __restrict__ Wsnap) {
    int idx = blockIdx.x * 256 + threadIdx.x;
    float v = wb[idx] + wc[idx];
    W[idx] = v;
    Wsnap[idx] = v;   // snapshot p=0 (t=0)
}

// full Gram per superchunk: G[p][s][t] = a_{p*256+s} . a_{p*256+t}
__global__ __launch_bounds__(256) void tm_gram(const float* __restrict__ a, float* __restrict__ G) {
    __shared__ float sl[64 * 65];
    __shared__ float tl[64 * 65];
    int bid = blockIdx.x;
    int p = bid >> 4, ts = (bid >> 2) & 3, tt = bid & 3;
    int tid = threadIdx.x;
    int c0 = (tid & 15) * 4, r0 = (tid >> 4) * 4;
    float acc[4][4] = {};
    for (int kt = 0; kt < 8; ++kt) {
        if (kt) __syncthreads();
        for (int l = tid; l < 64 * 16; l += 256) {
            int r = l >> 4, c4 = (l & 15) * 4;
            float4 v = *(const float4*)&a[(p * 256 + ts * 64 + r) * DD + kt * 64 + c4];
            sl[r * 65 + c4] = v.x; sl[r * 65 + c4 + 1] = v.y;
            sl[r * 65 + c4 + 2] = v.z; sl[r * 65 + c4 + 3] = v.w;
            float4 u = *(const float4*)&a[(p * 256 + tt * 64 + r) * DD + kt * 64 + c4];
            tl[r * 65 + c4] = u.x; tl[r * 65 + c4 + 1] = u.y;
            tl[r * 65 + c4 + 2] = u.z; tl[r * 65 + c4 + 3] = u.w;
        }
        __syncthreads();
        for (int kk = 0; kk < 64; ++kk) {
            float as[4], at[4];
#pragma unroll
            for (int q = 0; q < 4; ++q) { as[q] = sl[(r0 + q) * 65 + kk]; at[q] = tl[(c0 + q) * 65 + kk]; }
#pragma unroll
            for (int q = 0; q < 4; ++q)
#pragma unroll
                for (int w2 = 0; w2 < 4; ++w2) acc[q][w2] += as[q] * at[w2];
        }
    }
#pragma unroll
    for (int q = 0; q < 4; ++q) {
        float4 v = make_float4(acc[q][0], acc[q][1], acc[q][2], acc[q][3]);
        *(float4*)&G[p * 65536 + (ts * 64 + r0 + q) * 256 + tt * 64 + c0] = v;
    }
}

// P[t][i] = a[p*256+t][i] - sum_j W[i][j] a[p*256+t][j];  grid 32 (bt 0..3, bi 0..7)
__global__ __launch_bounds__(256) void tm_P(const float* __restrict__ a, const float* __restrict__ W,
                                            float* __restrict__ P, int p) {
    __shared__ float al[64 * 65];
    __shared__ float wl[64 * 65];
    int bid = blockIdx.x;
    int bt = bid & 3, bi = bid >> 2;
    int tid = threadIdx.x;
    int c0 = (tid & 15) * 4, r0 = (tid >> 4) * 4;
    float acc[4][4] = {};
    for (int kt = 0; kt < 8; ++kt) {
        if (kt) __syncthreads();
        for (int l = tid; l < 64 * 16; l += 256) {
            int r = l >> 4, c4 = (l & 15) * 4;
            float4 v = *(const float4*)&a[(p * 256 + bt * 64 + r) * DD + kt * 64 + c4];
            al[r * 65 + c4] = v.x; al[r * 65 + c4 + 1] = v.y;
            al[r * 65 + c4 + 2] = v.z; al[r * 65 + c4 + 3] = v.w;
            float4 u = *(const float4*)&W[(bi * 64 + r) * DD + kt * 64 + c4];
            wl[r * 65 + c4] = u.x; wl[r * 65 + c4 + 1] = u.y;
            wl[r * 65 + c4 + 2] = u.z; wl[r * 65 + c4 + 3] = u.w;
        }
        __syncthreads();
        for (int kk = 0; kk < 64; ++kk) {
            float af[4], bf[4];
#pragma unroll
            for (int q = 0; q < 4; ++q) { af[q] = al[(r0 + q) * 65 + kk]; bf[q] = wl[(c0 + q) * 65 + kk]; }
#pragma unroll
            for (int q = 0; q < 4; ++q)
#pragma unroll
                for (int w2 = 0; w2 < 4; ++w2) acc[q][w2] += af[q] * bf[w2];
        }
    }
#pragma unroll
    for (int q = 0; q < 4; ++q) {
        float4 av = *(const float4*)&a[(p * 256 + bt * 64 + r0 + q) * DD + bi * 64 + c0];
        float4 v = make_float4(av.x - acc[q][0], av.y - acc[q][1],
                               av.z - acc[q][2], av.w - acc[q][3]);
        *(float4*)&P[(bt * 64 + r0 + q) * DD + bi * 64 + c0] = v;
    }
}

// =====================================================================
// scanall v2: all 4 chunks of superchunk p, ONE block of 512 threads
// (thread = dim d). Per chunk j:
//   corr : acc[t] = P[j64+t][d] - LR*sum_{s<j64} G[s][j64+t]*CU[p256+s][d]
//   Gram : H[a][b] = b_a . b_b  (8 LDS dim-slices, 4x2 micro per thread)
//   scan : 64 steps; norm read DIRECTLY from H[t][t] (no reduce!), then
//          u-update in regs + rank-1 H update (predicated 4x2 tile).
// H-update correctness: u_x <- u_x - alpha_x*u_t with alpha_x = 0 for x<=t:
//   H[a][b] -= aB*H[a][t] + aA*H[t][b] - aA*aB*H[t][t]  covers all cases.
// Race audit: writes {a>t,b>t} disjoint from reads {row/col t}; one
// __syncthreads per step. CU RAW is same-thread (cup[t*DD+tid] written and
// cub[s*DD+tid] read by thread tid) -> program order suffices (R4/R5-proven).
// =====================================================================
__global__ __launch_bounds__(512) void tm_scanall(const float* __restrict__ P4,
                                                  const float* __restrict__ G,
                                                  float* __restrict__ CU, int p) {
    __shared__ float gl[64 * 64];    // G block (staged per use)
    __shared__ float H[64 * 68];     // u-Gram, pad 68 (float2-aligned)
    __shared__ float bsl[64 * 65];   // b dim-slice for Gram build
    const int tid = threadIdx.x;
    const int dloc = tid & 63, wv = tid >> 6;
    const int c0 = (tid & 31) * 2, r0 = (tid >> 5) * 4;   // 4x2 micro over 64x64
    const float* Gp = G + p * 65536;

    for (int j = 0; j < 4; ++j) {
        // ---- load P chunk (b init) into regs ----
        float acc[64];
#pragma unroll
        for (int t = 0; t < 64; ++t) acc[t] = P4[(j * 64 + t) * DD + tid];

        // ---- corr: fold in previous chunks of this superchunk ----
        for (int kb = 0; kb < j; ++kb) {
            __syncthreads();
            for (int l = tid; l < 64 * 16; l += 512) {
                int r = l >> 4, c4 = (l & 15) * 4;
                *(float4*)&gl[r * 64 + c4] = *(const float4*)&Gp[(kb * 64 + r) * 256 + j * 64 + c4];
            }
            __syncthreads();
            const float* cub = CU + (p * 256 + kb * 64) * DD;
            for (int s = 0; s < 64; ++s) {
                float cw = -LRF * cub[s * DD + tid];
#pragma unroll
                for (int t4 = 0; t4 < 64; t4 += 4) {
                    float4 g4 = *(const float4*)&gl[s * 64 + t4];
                    acc[t4]     += g4.x * cw; acc[t4 + 1] += g4.y * cw;
                    acc[t4 + 2] += g4.z * cw; acc[t4 + 3] += g4.w * cw;
                }
            }
        }

        // ---- Gram of b: H[a][b] = sum_d b_a[d] b_b[d], 8 dim-slices ----
        float h0 = 0, h1 = 0, h2 = 0, h3 = 0, h4 = 0, h5 = 0, h6 = 0, h7 = 0;
        for (int sl2 = 0; sl2 < 8; ++sl2) {
            __syncthreads();
            if (wv == sl2) {
#pragma unroll
                for (int t = 0; t < 64; ++t) bsl[t * 65 + dloc] = acc[t];
            }
            __syncthreads();
            for (int kk = 0; kk < 64; ++kk) {
                float a0 = bsl[(r0 + 0) * 65 + kk], a1 = bsl[(r0 + 1) * 65 + kk];
                float a2 = bsl[(r0 + 2) * 65 + kk], a3 = bsl[(r0 + 3) * 65 + kk];
                float b0v = bsl[(c0 + 0) * 65 + kk], b1v = bsl[(c0 + 1) * 65 + kk];
                h0 += a0 * b0v; h1 += a0 * b1v; h2 += a1 * b0v; h3 += a1 * b1v;
                h4 += a2 * b0v; h5 += a2 * b1v; h6 += a3 * b0v; h7 += a3 * b1v;
            }
        }
        __syncthreads();   // bsl reads done; gl free (corr done); H free (prev scan done)
        H[(r0 + 0) * 68 + c0] = h0; H[(r0 + 0) * 68 + c0 + 1] = h1;
        H[(r0 + 1) * 68 + c0] = h2; H[(r0 + 1) * 68 + c0 + 1] = h3;
        H[(r0 + 2) * 68 + c0] = h4; H[(r0 + 2) * 68 + c0 + 1] = h5;
        H[(r0 + 3) * 68 + c0] = h6; H[(r0 + 3) * 68 + c0 + 1] = h7;
        for (int l = tid; l < 64 * 16; l += 512) {
            int r = l >> 4, c4 = (l & 15) * 4;
            *(float4*)&gl[r * 64 + c4] = *(const float4*)&Gp[(j * 64 + r) * 256 + j * 64 + c4];
        }
        __syncthreads();

        // ---- scan: 64 steps, norms from H (no cross-lane reduce) ----
        float* cup = CU + (p * 256 + j * 64) * DD;
#pragma unroll
        for (int t = 0; t < 64; ++t) {
            float htt = H[t * 68 + t];
            float n2 = htt * gl[t * 64 + t];                     // ||u||^2 * ||a||^2
            float cs = (n2 > 0.25f) ? 0.5f * rsqrtf(n2) : 1.0f;  // min(1, CLIP/n)
            cup[t * DD + tid] = cs * acc[t];
            float alr = LRF * cs;
            float w0 = alr * acc[t];
            // u-update for t' > t
            {
                int t0 = t + 1;
#pragma unroll
                for (; t0 < 64 && (t0 & 3); ++t0) acc[t0] -= gl[t * 64 + t0] * w0;
#pragma unroll
                for (; t0 < 64; t0 += 4) {
                    float4 g4 = *(const float4*)&gl[t * 64 + t0];
                    acc[t0]     -= g4.x * w0; acc[t0 + 1] -= g4.y * w0;
                    acc[t0 + 2] -= g4.z * w0; acc[t0 + 3] -= g4.w * w0;
                }
            }
            // H-update: 4x2 tile, predicated (alpha_x = 0 for x <= t)
            {
                float4 ga = *(const float4*)&gl[t * 64 + r0];
                float aA0 = (r0 + 0 > t) ? alr * ga.x : 0.f;
                float aA1 = (r0 + 1 > t) ? alr * ga.y : 0.f;
                float aA2 = (r0 + 2 > t) ? alr * ga.z : 0.f;
                float aA3 = (r0 + 3 > t) ? alr * ga.w : 0.f;
                float aB0 = (c0 + 0 > t) ? alr * gl[t * 64 + c0] : 0.f;
                float aB1 = (c0 + 1 > t) ? alr * gl[t * 64 + c0 + 1] : 0.f;
                float hA0 = H[(r0 + 0) * 68 + t], hA1 = H[(r0 + 1) * 68 + t];
                float hA2 = H[(r0 + 2) * 68 + t], hA3 = H[(r0 + 3) * 68 + t];
                float hB0 = H[t * 68 + c0], hB1 = H[t * 68 + c0 + 1];
                H[(r0 + 0) * 68 + c0]     += -aB0 * hA0 - aA0 * hB0 + aA0 * aB0 * htt;
                H[(r0 + 0) * 68 + c0 + 1] += -aB1 * hA0 - aA0 * hB1 + aA0 * aB1 * htt;
                H[(r0 + 1) * 68 + c0]     += -aB0 * hA1 - aA1 * hB0 + aA1 * aB0 * htt;
                H[(r0 + 1) * 68 + c0 + 1] += -aB1 * hA1 - aA1 * hB1 + aA1 * aB1 * htt;
                H[(r0 + 2) * 68 + c0]     += -aB0 * hA2 - aA2 * hB0 + aA2 * aB0 * htt;
                H[(r0 + 2) * 68 + c0 + 1] += -aB1 * hA2 - aA2 * hB1 + aA2 * aB1 * htt;
                H[(r0 + 3) * 68 + c0]     += -aB0 * hA3 - aA3 * hB0 + aA3 * aB0 * htt;
                H[(r0 + 3) * 68 + c0 + 1] += -aB1 * hA3 - aA3 * hB1 + aA3 * aB1 * htt;
            }
            __syncthreads();
        }
    }
}

// W += LR * sum_{r in sc p} cu_r (x) a_r  (rank-256); optional snapshot / final output
__global__ void tm_wupd(const float* __restrict__ a, const float* __restrict__ cu,
                        float* __restrict__ W, float* __restrict__ Wsnap,
                        const float* __restrict__ wb, float* __restrict__ outW,
                        int p, int snap_p, int is_final) {
    int idx = blockIdx.x * 256 + threadIdx.x;
    int i = idx >> 9, jj = idx & 511;
    const float* cb = cu + p * 256 * DD + i;
    const float* ab = a + p * 256 * DD + jj;
    float s = 0.f;
#pragma unroll 8
    for (int r = 0; r < 256; ++r) s += cb[r * DD] * ab[r * DD];
    float w = W[idx] + LRF * s;
    W[idx] = w;
    if (snap_p >= 0) Wsnap[snap_p * DD * DD + idx] = w;
    if (is_final) outW[idx] = w - wb[idx];
}

// ---------------- phase 3 (parallel output) ----------------

// S[p][rloc][s] = x[row] . a[p*256+s]
__global__ __launch_bounds__(256) void tm_score(const float* __restrict__ x, const float* __restrict__ a,
                                                float* __restrict__ S) {
    __shared__ float al[64 * 65];
    __shared__ float bl[64 * 65];
    int bid = blockIdx.x;
    int st = bid & 3, rt = (bid >> 2) & 31, p = bid >> 7;
    int tid = threadIdx.x;
    int c0 = (tid & 15) * 4, r0 = (tid >> 4) * 4;
    float acc[4][4] = {};
    for (int kt = 0; kt < 8; ++kt) {
        if (kt) __syncthreads();
        for (int l = tid; l < 64 * 16; l += 256) {
            int r = l >> 4, c4 = (l & 15) * 4;
            int rloc = rt * 64 + r;
            int grow = ((rloc >> 8) * TT) + p * 256 + (rloc & 255);
            float4 v = *(const float4*)&x[grow * DD + kt * 64 + c4];
            al[r * 65 + c4] = v.x; al[r * 65 + c4 + 1] = v.y;
            al[r * 65 + c4 + 2] = v.z; al[r * 65 + c4 + 3] = v.w;
            float4 u = *(const float4*)&a[(p * 256 + st * 64 + r) * DD + kt * 64 + c4];
            bl[r * 65 + c4] = u.x; bl[r * 65 + c4 + 1] = u.y;
            bl[r * 65 + c4 + 2] = u.z; bl[r * 65 + c4 + 3] = u.w;
        }
        __syncthreads();
        for (int kk = 0; kk < 64; ++kk) {
            float af[4], bf[4];
#pragma unroll
            for (int q = 0; q < 4; ++q) { af[q] = al[(r0 + q) * 65 + kk]; bf[q] = bl[(c0 + q) * 65 + kk]; }
#pragma unroll
            for (int q = 0; q < 4; ++q)
#pragma unroll
                for (int w2 = 0; w2 < 4; ++w2) acc[q][w2] += af[q] * bf[w2];
        }
    }
#pragma unroll
    for (int q = 0; q < 4; ++q) {
        int rloc = rt * 64 + r0 + q;
        float4 v = make_float4(acc[q][0], acc[q][1], acc[q][2], acc[q][3]);
        *(float4*)&S[(p * 2048 + rloc) * 256 + st * 64 + c0] = v;
    }
}

// FUSED mem+apply+gate per 64x64 out tile:
// out[row][i] = sigmoid(x.gw[i]+gb[i]) * ( x.WS[p][i] + LR*sum_{s<tloc} S*cu )
__global__ __launch_bounds__(256) void tm_fused(const float* __restrict__ x, const float* __restrict__ Wsnap,
                                                const float* __restrict__ S, const float* __restrict__ cu,
                                                const float* __restrict__ gw, const float* __restrict__ gb,
                                                float* __restrict__ out) {
    __shared__ float al[64 * 65];
    __shared__ float bl[64 * 65];
    int bid = blockIdx.x;
    int p = bid >> 8, rem = bid & 255, rt = rem >> 3, it = rem & 7;
    int tid = threadIdx.x;
    int c0 = (tid & 15) * 4, r0 = (tid >> 4) * 4;
    int growbase = (rt >> 2) * TT + p * 256 + (rt & 3) * 64;
    const float* xb = x + growbase * DD;
    const float* Wp = Wsnap + p * DD * DD + it * 64 * DD;
    const float* gwp = gw + it * 64 * DD;

    float accM[4][4] = {};
    float accG[4][4] = {};
    float accA[4][4] = {};

    for (int kt = 0; kt < 8; ++kt) {
        if (kt) __syncthreads();
        for (int l = tid; l < 64 * 16; l += 256) {
            int r = l >> 4, c4 = (l & 15) * 4;
            float4 v = *(const float4*)&xb[r * DD + kt * 64 + c4];
            al[r * 65 + c4] = v.x; al[r * 65 + c4 + 1] = v.y;
            al[r * 65 + c4 + 2] = v.z; al[r * 65 + c4 + 3] = v.w;
            float4 u = *(const float4*)&Wp[r * DD + kt * 64 + c4];
            bl[r * 65 + c4] = u.x; bl[r * 65 + c4 + 1] = u.y;
            bl[r * 65 + c4 + 2] = u.z; bl[r * 65 + c4 + 3] = u.w;
        }
        __syncthreads();
        for (int kk = 0; kk < 64; ++kk) {
            float af[4], bf[4];
#pragma unroll
            for (int q = 0; q < 4; ++q) { af[q] = al[(r0 + q) * 65 + kk]; bf[q] = bl[(c0 + q) * 65 + kk]; }
#pragma unroll
            for (int q = 0; q < 4; ++q)
#pragma unroll
                for (int w2 = 0; w2 < 4; ++w2) accM[q][w2] += af[q] * bf[w2];
        }
        __syncthreads();
        for (int l = tid; l < 64 * 16; l += 256) {
            int r = l >> 4, c4 = (l & 15) * 4;
            float4 u = *(const float4*)&gwp[r * DD + kt * 64 + c4];
            bl[r * 65 + c4] = u.x; bl[r * 65 + c4 + 1] = u.y;
            bl[r * 65 + c4 + 2] = u.z; bl[r * 65 + c4 + 3] = u.w;
        }
        __syncthreads();
        for (int kk = 0; kk < 64; ++kk) {
            float af[4], bf[4];
#pragma unroll
            for (int q = 0; q < 4; ++q) { af[q] = al[(r0 + q) * 65 + kk]; bf[q] = bl[(c0 + q) * 65 + kk]; }
#pragma unroll
            for (int q = 0; q < 4; ++q)
#pragma unroll
                for (int w2 = 0; w2 < 4; ++w2) accG[q][w2] += af[q] * bf[w2];
        }
    }

    for (int kt = 0; kt < 4; ++kt) {
        __syncthreads();
        for (int l = tid; l < 64 * 16; l += 256) {
            int r = l >> 4, c4 = (l & 15) * 4;
            int rloc = rt * 64 + r;
            int tq = rloc & 255;
            float4 v = *(const float4*)&S[(p * 2048 + rloc) * 256 + kt * 64 + c4];
            int sb = kt * 64 + c4;
            al[r * 65 + c4]     = (sb + 0 < tq) ? v.x : 0.f;
            al[r * 65 + c4 + 1] = (sb + 1 < tq) ? v.y : 0.f;
            al[r * 65 + c4 + 2] = (sb + 2 < tq) ? v.z : 0.f;
            al[r * 65 + c4 + 3] = (sb + 3 < tq) ? v.w : 0.f;
            float4 u = *(const float4*)&cu[(p * 256 + kt * 64 + r) * DD + it * 64 + c4];
            bl[r * 65 + c4] = u.x; bl[r * 65 + c4 + 1] = u.y;
            bl[r * 65 + c4 + 2] = u.z; bl[r * 65 + c4 + 3] = u.w;
        }
        __syncthreads();
        for (int kk = 0; kk < 64; ++kk) {
            float af[4], bf[4];
#pragma unroll
            for (int q = 0; q < 4; ++q) { af[q] = al[(r0 + q) * 65 + kk]; bf[q] = bl[kk * 65 + c0 + q]; }
#pragma unroll
            for (int q = 0; q < 4; ++q)
#pragma unroll
                for (int w2 = 0; w2 < 4; ++w2) accA[q][w2] += af[q] * bf[w2];
        }
    }

#pragma unroll
    for (int q = 0; q < 4; ++q) {
        float4 v;
        float z0 = accG[q][0] + gb[it * 64 + c0 + 0];
        float z1 = accG[q][1] + gb[it * 64 + c0 + 1];
        float z2 = accG[q][2] + gb[it * 64 + c0 + 2];
        float z3 = accG[q][3] + gb[it * 64 + c0 + 3];
        v.x = (accM[q][0] + LRF * accA[q][0]) / (1.f + expf(-z0));
        v.y = (accM[q][1] + LRF * accA[q][1]) / (1.f + expf(-z1));
        v.z = (accM[q][2] + LRF * accA[q][2]) / (1.f + expf(-z2));
        v.w = (accM[q][3] + LRF * accA[q][3]) / (1.f + expf(-z3));
        *(float4*)&out[(growbase + r0 + q) * DD + it * 64 + c0] = v;
    }
}

extern "C" void kernel_launch(void* const* d_in, const int* in_sizes, int n_in,
                              void* d_out, int out_size, void* d_ws, size_t ws_size,
                              hipStream_t stream) {
    const float* x   = (const float*)d_in[0];
    const float* Wc0 = (const float*)d_in[1];
    const float* Wb  = (const float*)d_in[2];
    const float* gw  = (const float*)d_in[3];
    const float* gb  = (const float*)d_in[4];
    float* out  = (float*)d_out;
    float* outW = out + BB * TT * DD;

    float* ws = (float*)d_ws;
    float* A  = ws + OFF_A;
    float* CU = ws + OFF_CU;
    float* G  = ws + OFF_G;
    float* P  = ws + OFF_P;
    float* W  = ws + OFF_W;
    float* WS = ws + OFF_WS;
    float* S  = ws + OFF_S;

    tm_mean<<<(TT * DD) / 256, 256, 0, stream>>>(x, A);
    tm_init<<<(DD * DD) / 256, 256, 0, stream>>>(Wb, Wc0, W, WS);
    tm_gram<<<256, 256, 0, stream>>>(A, G);
    tm_P<<<32, 256, 0, stream>>>(A, W, P, 0);

    for (int p = 0; p < 16; ++p) {
        tm_scanall<<<1, 512, 0, stream>>>(P, G, CU, p);
        if (p < 15) {
            tm_wupd<<<(DD * DD) / 256, 256, 0, stream>>>(A, CU, W, WS, Wb, outW, p, p + 1, 0);
            tm_P<<<32, 256, 0, stream>>>(A, W, P, p + 1);
        }
    }
    tm_wupd<<<(DD * DD) / 256, 256, 0, stream>>>(A, CU, W, WS, Wb, outW, 15, -1, 1);

    tm_score<<<16 * 128, 256, 0, stream>>>(x, A, S);
    tm_fused<<<16 * 256, 256, 0, stream>>>(x, WS, S, CU, gw, gb, out);
}

// Round 7
// 20583.125 us; speedup vs baseline: 1.0225x; 1.0225x over previous
//
#include <hip/hip_runtime.h>
#include <math.h>

#define BB 8
#define TT 4096
#define DD 512
constexpr float LRF = 0.01f;

// ---------------- workspace layout (floats) ----------------
// A  : [4096][512]        mean of x over batch
// CU : [4096][512]        c_s * u_s
// G  : [16][256][256]     per-superchunk Gram of A
// P  : [256][512]         A_sc - A_sc @ W(p)^T   (reused per superchunk)
// W  : [512][512]         running W_base + W_c
// WS : [16][512][512]     W snapshots at t = 256*p
// S  : [16][2048][256]    attention scores
#define OFF_A  0
#define OFF_CU 2097152
#define OFF_G  4194304
#define OFF_P  5242880
#define OFF_W  5406720
#define OFF_WS 5668864
#define OFF_S  9863168

__global__ void tm_mean(const float* __restrict__ x, float* __restrict__ a) {
    int idx = blockIdx.x * 256 + threadIdx.x;   // t*D + d
    float s = 0.f;
#pragma unroll
    for (int b = 0; b < BB; ++b) s += x[b * (TT * DD) + idx];
    a[idx] = s * 0.125f;
}

__global__ void tm_init(const float* __restrict__ wb, const float* __restrict__ wc,
                        float* __restrict__ W, float* __restrict__ Wsnap) {
    int idx = blockIdx.x * 256 + threadIdx.x;
    float v = wb[idx] + wc[idx];
    W[idx] = v;
    Wsnap[idx] = v;   // snapshot p=0 (t=0)
}

// full Gram per superchunk: G[p][s][t] = a_{p*256+s} . a_{p*256+t}
__global__ __launch_bounds__(256) void tm_gram(const float* __restrict__ a, float* __restrict__ G) {
    __shared__ float sl[64 * 65];
    __shared__ float tl[64 * 65];
    int bid = blockIdx.x;
    int p = bid >> 4, ts = (bid >> 2) & 3, tt = bid & 3;
    int tid = threadIdx.x;
    int c0 = (tid & 15) * 4, r0 = (tid >> 4) * 4;
    float acc[4][4] = {};
    for (int kt = 0; kt < 8; ++kt) {
        if (kt) __syncthreads();
        for (int l = tid; l < 64 * 16; l += 256) {
            int r = l >> 4, c4 = (l & 15) * 4;
            float4 v = *(const float4*)&a[(p * 256 + ts * 64 + r) * DD + kt * 64 + c4];
            sl[r * 65 + c4] = v.x; sl[r * 65 + c4 + 1] = v.y;
            sl[r * 65 + c4 + 2] = v.z; sl[r * 65 + c4 + 3] = v.w;
            float4 u = *(const float4*)&a[(p * 256 + tt * 64 + r) * DD + kt * 64 + c4];
            tl[r * 65 + c4] = u.x; tl[r * 65 + c4 + 1] = u.y;
            tl[r * 65 + c4 + 2] = u.z; tl[r * 65 + c4 + 3] = u.w;
        }
        __syncthreads();
        for (int kk = 0; kk < 64; ++kk) {
            float as[4], at[4];
#pragma unroll
            for (int q = 0; q < 4; ++q) { as[q] = sl[(r0 + q) * 65 + kk]; at[q] = tl[(c0 + q) * 65 + kk]; }
#pragma unroll
            for (int q = 0; q < 4; ++q)
#pragma unroll
                for (int w2 = 0; w2 < 4; ++w2) acc[q][w2] += as[q] * at[w2];
        }
    }
#pragma unroll
    for (int q = 0; q < 4; ++q) {
        float4 v = make_float4(acc[q][0], acc[q][1], acc[q][2], acc[q][3]);
        *(float4*)&G[p * 65536 + (ts * 64 + r0 + q) * 256 + tt * 64 + c0] = v;
    }
}

// P[t][i] = a[p*256+t][i] - sum_j W[i][j] a[p*256+t][j];  grid 32 (bt 0..3, bi 0..7)
__global__ __launch_bounds__(256) void tm_P(const float* __restrict__ a, const float* __restrict__ W,
                                            float* __restrict__ P, int p) {
    __shared__ float al[64 * 65];
    __shared__ float wl[64 * 65];
    int bid = blockIdx.x;
    int bt = bid & 3, bi = bid >> 2;
    int tid = threadIdx.x;
    int c0 = (tid & 15) * 4, r0 = (tid >> 4) * 4;
    float acc[4][4] = {};
    for (int kt = 0; kt < 8; ++kt) {
        if (kt) __syncthreads();
        for (int l = tid; l < 64 * 16; l += 256) {
            int r = l >> 4, c4 = (l & 15) * 4;
            float4 v = *(const float4*)&a[(p * 256 + bt * 64 + r) * DD + kt * 64 + c4];
            al[r * 65 + c4] = v.x; al[r * 65 + c4 + 1] = v.y;
            al[r * 65 + c4 + 2] = v.z; al[r * 65 + c4 + 3] = v.w;
            float4 u = *(const float4*)&W[(bi * 64 + r) * DD + kt * 64 + c4];
            wl[r * 65 + c4] = u.x; wl[r * 65 + c4 + 1] = u.y;
            wl[r * 65 + c4 + 2] = u.z; wl[r * 65 + c4 + 3] = u.w;
        }
        __syncthreads();
        for (int kk = 0; kk < 64; ++kk) {
            float af[4], bf[4];
#pragma unroll
            for (int q = 0; q < 4; ++q) { af[q] = al[(r0 + q) * 65 + kk]; bf[q] = wl[(c0 + q) * 65 + kk]; }
#pragma unroll
            for (int q = 0; q < 4; ++q)
#pragma unroll
                for (int w2 = 0; w2 < 4; ++w2) acc[q][w2] += af[q] * bf[w2];
        }
    }
#pragma unroll
    for (int q = 0; q < 4; ++q) {
        float4 av = *(const float4*)&a[(p * 256 + bt * 64 + r0 + q) * DD + bi * 64 + c0];
        float4 v = make_float4(av.x - acc[q][0], av.y - acc[q][1],
                               av.z - acc[q][2], av.w - acc[q][3]);
        *(float4*)&P[(bt * 64 + r0 + q) * DD + bi * 64 + c0] = v;
    }
}

// =====================================================================
// scanall v2.1: identical to v2 except __launch_bounds__(512, 2).
// R6 post-mortem: plain (512) let the compiler target 4 waves/SIMD ->
// 128-VGPR cap -> acc[64]+temps spilled to scratch (WRITE_SIZE 5.2MB vs
// 0.55MB algorithmic; VALUBusy ~13% of the one CU). (512,2) = 2 waves/EU
// = exactly our 8-wave block -> 256-VGPR budget -> no spill.
// =====================================================================
__global__ __launch_bounds__(512, 2) void tm_scanall(const float* __restrict__ P4,
                                                     const float* __restrict__ G,
                                                     float* __restrict__ CU, int p) {
    __shared__ float gl[64 * 64];    // G block (staged per use)
    __shared__ float H[64 * 68];     // u-Gram, pad 68 (float2-aligned)
    __shared__ float bsl[64 * 65];   // b dim-slice for Gram build
    const int tid = threadIdx.x;
    const int dloc = tid & 63, wv = tid >> 6;
    const int c0 = (tid & 31) * 2, r0 = (tid >> 5) * 4;   // 4x2 micro over 64x64
    const float* Gp = G + p * 65536;

    for (int j = 0; j < 4; ++j) {
        // ---- load P chunk (b init) into regs ----
        float acc[64];
#pragma unroll
        for (int t = 0; t < 64; ++t) acc[t] = P4[(j * 64 + t) * DD + tid];

        // ---- corr: fold in previous chunks of this superchunk ----
        for (int kb = 0; kb < j; ++kb) {
            __syncthreads();
            for (int l = tid; l < 64 * 16; l += 512) {
                int r = l >> 4, c4 = (l & 15) * 4;
                *(float4*)&gl[r * 64 + c4] = *(const float4*)&Gp[(kb * 64 + r) * 256 + j * 64 + c4];
            }
            __syncthreads();
            const float* cub = CU + (p * 256 + kb * 64) * DD;
            for (int s = 0; s < 64; ++s) {
                float cw = -LRF * cub[s * DD + tid];
#pragma unroll
                for (int t4 = 0; t4 < 64; t4 += 4) {
                    float4 g4 = *(const float4*)&gl[s * 64 + t4];
                    acc[t4]     += g4.x * cw; acc[t4 + 1] += g4.y * cw;
                    acc[t4 + 2] += g4.z * cw; acc[t4 + 3] += g4.w * cw;
                }
            }
        }

        // ---- Gram of b: H[a][b] = sum_d b_a[d] b_b[d], 8 dim-slices ----
        float h0 = 0, h1 = 0, h2 = 0, h3 = 0, h4 = 0, h5 = 0, h6 = 0, h7 = 0;
        for (int sl2 = 0; sl2 < 8; ++sl2) {
            __syncthreads();
            if (wv == sl2) {
#pragma unroll
                for (int t = 0; t < 64; ++t) bsl[t * 65 + dloc] = acc[t];
            }
            __syncthreads();
            for (int kk = 0; kk < 64; ++kk) {
                float a0 = bsl[(r0 + 0) * 65 + kk], a1 = bsl[(r0 + 1) * 65 + kk];
                float a2 = bsl[(r0 + 2) * 65 + kk], a3 = bsl[(r0 + 3) * 65 + kk];
                float b0v = bsl[(c0 + 0) * 65 + kk], b1v = bsl[(c0 + 1) * 65 + kk];
                h0 += a0 * b0v; h1 += a0 * b1v; h2 += a1 * b0v; h3 += a1 * b1v;
                h4 += a2 * b0v; h5 += a2 * b1v; h6 += a3 * b0v; h7 += a3 * b1v;
            }
        }
        __syncthreads();   // bsl reads done; gl free (corr done); H free (prev scan done)
        H[(r0 + 0) * 68 + c0] = h0; H[(r0 + 0) * 68 + c0 + 1] = h1;
        H[(r0 + 1) * 68 + c0] = h2; H[(r0 + 1) * 68 + c0 + 1] = h3;
        H[(r0 + 2) * 68 + c0] = h4; H[(r0 + 2) * 68 + c0 + 1] = h5;
        H[(r0 + 3) * 68 + c0] = h6; H[(r0 + 3) * 68 + c0 + 1] = h7;
        for (int l = tid; l < 64 * 16; l += 512) {
            int r = l >> 4, c4 = (l & 15) * 4;
            *(float4*)&gl[r * 64 + c4] = *(const float4*)&Gp[(j * 64 + r) * 256 + j * 64 + c4];
        }
        __syncthreads();

        // ---- scan: 64 steps, norms from H (no cross-lane reduce) ----
        float* cup = CU + (p * 256 + j * 64) * DD;
#pragma unroll
        for (int t = 0; t < 64; ++t) {
            float htt = H[t * 68 + t];
            float n2 = htt * gl[t * 64 + t];                     // ||u||^2 * ||a||^2
            float cs = (n2 > 0.25f) ? 0.5f * rsqrtf(n2) : 1.0f;  // min(1, CLIP/n)
            cup[t * DD + tid] = cs * acc[t];
            float alr = LRF * cs;
            float w0 = alr * acc[t];
            // u-update for t' > t
            {
                int t0 = t + 1;
#pragma unroll
                for (; t0 < 64 && (t0 & 3); ++t0) acc[t0] -= gl[t * 64 + t0] * w0;
#pragma unroll
                for (; t0 < 64; t0 += 4) {
                    float4 g4 = *(const float4*)&gl[t * 64 + t0];
                    acc[t0]     -= g4.x * w0; acc[t0 + 1] -= g4.y * w0;
                    acc[t0 + 2] -= g4.z * w0; acc[t0 + 3] -= g4.w * w0;
                }
            }
            // H-update: 4x2 tile, predicated (alpha_x = 0 for x <= t)
            {
                float4 ga = *(const float4*)&gl[t * 64 + r0];
                float aA0 = (r0 + 0 > t) ? alr * ga.x : 0.f;
                float aA1 = (r0 + 1 > t) ? alr * ga.y : 0.f;
                float aA2 = (r0 + 2 > t) ? alr * ga.z : 0.f;
                float aA3 = (r0 + 3 > t) ? alr * ga.w : 0.f;
                float aB0 = (c0 + 0 > t) ? alr * gl[t * 64 + c0] : 0.f;
                float aB1 = (c0 + 1 > t) ? alr * gl[t * 64 + c0 + 1] : 0.f;
                float hA0 = H[(r0 + 0) * 68 + t], hA1 = H[(r0 + 1) * 68 + t];
                float hA2 = H[(r0 + 2) * 68 + t], hA3 = H[(r0 + 3) * 68 + t];
                float hB0 = H[t * 68 + c0], hB1 = H[t * 68 + c0 + 1];
                H[(r0 + 0) * 68 + c0]     += -aB0 * hA0 - aA0 * hB0 + aA0 * aB0 * htt;
                H[(r0 + 0) * 68 + c0 + 1] += -aB1 * hA0 - aA0 * hB1 + aA0 * aB1 * htt;
                H[(r0 + 1) * 68 + c0]     += -aB0 * hA1 - aA1 * hB0 + aA1 * aB0 * htt;
                H[(r0 + 1) * 68 + c0 + 1] += -aB1 * hA1 - aA1 * hB1 + aA1 * aB1 * htt;
                H[(r0 + 2) * 68 + c0]     += -aB0 * hA2 - aA2 * hB0 + aA2 * aB0 * htt;
                H[(r0 + 2) * 68 + c0 + 1] += -aB1 * hA2 - aA2 * hB1 + aA2 * aB1 * htt;
                H[(r0 + 3) * 68 + c0]     += -aB0 * hA3 - aA3 * hB0 + aA3 * aB0 * htt;
                H[(r0 + 3) * 68 + c0 + 1] += -aB1 * hA3 - aA3 * hB1 + aA3 * aB1 * htt;
            }
            __syncthreads();
        }
    }
}

// W += LR * sum_{r in sc p} cu_r (x) a_r  (rank-256); optional snapshot / final output
__global__ void tm_wupd(const float* __restrict__ a, const float* __restrict__ cu,
                        float* __restrict__ W, float* __restrict__ Wsnap,
                        const float* __restrict__ wb, float* __restrict__ outW,
                        int p, int snap_p, int is_final) {
    int idx = blockIdx.x * 256 + threadIdx.x;
    int i = idx >> 9, jj = idx & 511;
    const float* cb = cu + p * 256 * DD + i;
    const float* ab = a + p * 256 * DD + jj;
    float s = 0.f;
#pragma unroll 8
    for (int r = 0; r < 256; ++r) s += cb[r * DD] * ab[r * DD];
    float w = W[idx] + LRF * s;
    W[idx] = w;
    if (snap_p >= 0) Wsnap[snap_p * DD * DD + idx] = w;
    if (is_final) outW[idx] = w - wb[idx];
}

// ---------------- phase 3 (parallel output) ----------------

// S[p][rloc][s] = x[row] . a[p*256+s]
__global__ __launch_bounds__(256) void tm_score(const float* __restrict__ x, const float* __restrict__ a,
                                                float* __restrict__ S) {
    __shared__ float al[64 * 65];
    __shared__ float bl[64 * 65];
    int bid = blockIdx.x;
    int st = bid & 3, rt = (bid >> 2) & 31, p = bid >> 7;
    int tid = threadIdx.x;
    int c0 = (tid & 15) * 4, r0 = (tid >> 4) * 4;
    float acc[4][4] = {};
    for (int kt = 0; kt < 8; ++kt) {
        if (kt) __syncthreads();
        for (int l = tid; l < 64 * 16; l += 256) {
            int r = l >> 4, c4 = (l & 15) * 4;
            int rloc = rt * 64 + r;
            int grow = ((rloc >> 8) * TT) + p * 256 + (rloc & 255);
            float4 v = *(const float4*)&x[grow * DD + kt * 64 + c4];
            al[r * 65 + c4] = v.x; al[r * 65 + c4 + 1] = v.y;
            al[r * 65 + c4 + 2] = v.z; al[r * 65 + c4 + 3] = v.w;
            float4 u = *(const float4*)&a[(p * 256 + st * 64 + r) * DD + kt * 64 + c4];
            bl[r * 65 + c4] = u.x; bl[r * 65 + c4 + 1] = u.y;
            bl[r * 65 + c4 + 2] = u.z; bl[r * 65 + c4 + 3] = u.w;
        }
        __syncthreads();
        for (int kk = 0; kk < 64; ++kk) {
            float af[4], bf[4];
#pragma unroll
            for (int q = 0; q < 4; ++q) { af[q] = al[(r0 + q) * 65 + kk]; bf[q] = bl[(c0 + q) * 65 + kk]; }
#pragma unroll
            for (int q = 0; q < 4; ++q)
#pragma unroll
                for (int w2 = 0; w2 < 4; ++w2) acc[q][w2] += af[q] * bf[w2];
        }
    }
#pragma unroll
    for (int q = 0; q < 4; ++q) {
        int rloc = rt * 64 + r0 + q;
        float4 v = make_float4(acc[q][0], acc[q][1], acc[q][2], acc[q][3]);
        *(float4*)&S[(p * 2048 + rloc) * 256 + st * 64 + c0] = v;
    }
}

// FUSED mem+apply+gate per 64x64 out tile:
// out[row][i] = sigmoid(x.gw[i]+gb[i]) * ( x.WS[p][i] + LR*sum_{s<tloc} S*cu )
__global__ __launch_bounds__(256) void tm_fused(const float* __restrict__ x, const float* __restrict__ Wsnap,
                                                const float* __restrict__ S, const float* __restrict__ cu,
                                                const float* __restrict__ gw, const float* __restrict__ gb,
                                                float* __restrict__ out) {
    __shared__ float al[64 * 65];
    __shared__ float bl[64 * 65];
    int bid = blockIdx.x;
    int p = bid >> 8, rem = bid & 255, rt = rem >> 3, it = rem & 7;
    int tid = threadIdx.x;
    int c0 = (tid & 15) * 4, r0 = (tid >> 4) * 4;
    int growbase = (rt >> 2) * TT + p * 256 + (rt & 3) * 64;
    const float* xb = x + growbase * DD;
    const float* Wp = Wsnap + p * DD * DD + it * 64 * DD;
    const float* gwp = gw + it * 64 * DD;

    float accM[4][4] = {};
    float accG[4][4] = {};
    float accA[4][4] = {};

    for (int kt = 0; kt < 8; ++kt) {
        if (kt) __syncthreads();
        for (int l = tid; l < 64 * 16; l += 256) {
            int r = l >> 4, c4 = (l & 15) * 4;
            float4 v = *(const float4*)&xb[r * DD + kt * 64 + c4];
            al[r * 65 + c4] = v.x; al[r * 65 + c4 + 1] = v.y;
            al[r * 65 + c4 + 2] = v.z; al[r * 65 + c4 + 3] = v.w;
            float4 u = *(const float4*)&Wp[r * DD + kt * 64 + c4];
            bl[r * 65 + c4] = u.x; bl[r * 65 + c4 + 1] = u.y;
            bl[r * 65 + c4 + 2] = u.z; bl[r * 65 + c4 + 3] = u.w;
        }
        __syncthreads();
        for (int kk = 0; kk < 64; ++kk) {
            float af[4], bf[4];
#pragma unroll
            for (int q = 0; q < 4; ++q) { af[q] = al[(r0 + q) * 65 + kk]; bf[q] = bl[(c0 + q) * 65 + kk]; }
#pragma unroll
            for (int q = 0; q < 4; ++q)
#pragma unroll
                for (int w2 = 0; w2 < 4; ++w2) accM[q][w2] += af[q] * bf[w2];
        }
        __syncthreads();
        for (int l = tid; l < 64 * 16; l += 256) {
            int r = l >> 4, c4 = (l & 15) * 4;
            float4 u = *(const float4*)&gwp[r * DD + kt * 64 + c4];
            bl[r * 65 + c4] = u.x; bl[r * 65 + c4 + 1] = u.y;
            bl[r * 65 + c4 + 2] = u.z; bl[r * 65 + c4 + 3] = u.w;
        }
        __syncthreads();
        for (int kk = 0; kk < 64; ++kk) {
            float af[4], bf[4];
#pragma unroll
            for (int q = 0; q < 4; ++q) { af[q] = al[(r0 + q) * 65 + kk]; bf[q] = bl[(c0 + q) * 65 + kk]; }
#pragma unroll
            for (int q = 0; q < 4; ++q)
#pragma unroll
                for (int w2 = 0; w2 < 4; ++w2) accG[q][w2] += af[q] * bf[w2];
        }
    }

    for (int kt = 0; kt < 4; ++kt) {
        __syncthreads();
        for (int l = tid; l < 64 * 16; l += 256) {
            int r = l >> 4, c4 = (l & 15) * 4;
            int rloc = rt * 64 + r;
            int tq = rloc & 255;
            float4 v = *(const float4*)&S[(p * 2048 + rloc) * 256 + kt * 64 + c4];
            int sb = kt * 64 + c4;
            al[r * 65 + c4]     = (sb + 0 < tq) ? v.x : 0.f;
            al[r * 65 + c4 + 1] = (sb + 1 < tq) ? v.y : 0.f;
            al[r * 65 + c4 + 2] = (sb + 2 < tq) ? v.z : 0.f;
            al[r * 65 + c4 + 3] = (sb + 3 < tq) ? v.w : 0.f;
            float4 u = *(const float4*)&cu[(p * 256 + kt * 64 + r) * DD + it * 64 + c4];
            bl[r * 65 + c4] = u.x; bl[r * 65 + c4 + 1] = u.y;
            bl[r * 65 + c4 + 2] = u.z; bl[r * 65 + c4 + 3] = u.w;
        }
        __syncthreads();
        for (int kk = 0; kk < 64; ++kk) {
            float af[4], bf[4];
#pragma unroll
            for (int q = 0; q < 4; ++q) { af[q] = al[(r0 + q) * 65 + kk]; bf[q] = bl[kk * 65 + c0 + q]; }
#pragma unroll
            for (int q = 0; q < 4; ++q)
#pragma unroll
                for (int w2 = 0; w2 < 4; ++w2) accA[q][w2] += af[q] * bf[w2];
        }
    }

#pragma unroll
    for (int q = 0; q < 4; ++q) {
        float4 v;
        float z0 = accG[q][0] + gb[it * 64 + c0 + 0];
        float z1 = accG[q][1] + gb[it * 64 + c0 + 1];
        float z2 = accG[q][2] + gb[it * 64 + c0 + 2];
        float z3 = accG[q][3] + gb[it * 64 + c0 + 3];
        v.x = (accM[q][0] + LRF * accA[q][0]) / (1.f + expf(-z0));
        v.y = (accM[q][1] + LRF * accA[q][1]) / (1.f + expf(-z1));
        v.z = (accM[q][2] + LRF * accA[q][2]) / (1.f + expf(-z2));
        v.w = (accM[q][3] + LRF * accA[q][3]) / (1.f + expf(-z3));
        *(float4*)&out[(growbase + r0 + q) * DD + it * 64 + c0] = v;
    }
}

extern "C" void kernel_launch(void* const* d_in, const int* in_sizes, int n_in,
                              void* d_out, int out_size, void* d_ws, size_t ws_size,
                              hipStream_t stream) {
    const float* x   = (const float*)d_in[0];
    const float* Wc0 = (const float*)d_in[1];
    const float* Wb  = (const float*)d_in[2];
    const float* gw  = (const float*)d_in[3];
    const float* gb  = (const float*)d_in[4];
    float* out  = (float*)d_out;
    float* outW = out + BB * TT * DD;

    float* ws = (float*)d_ws;
    float* A  = ws + OFF_A;
    float* CU = ws + OFF_CU;
    float* G  = ws + OFF_G;
    float* P  = ws + OFF_P;
    float* W  = ws + OFF_W;
    float* WS = ws + OFF_WS;
    float* S  = ws + OFF_S;

    tm_mean<<<(TT * DD) / 256, 256, 0, stream>>>(x, A);
    tm_init<<<(DD * DD) / 256, 256, 0, stream>>>(Wb, Wc0, W, WS);
    tm_gram<<<256, 256, 0, stream>>>(A, G);
    tm_P<<<32, 256, 0, stream>>>(A, W, P, 0);

    for (int p = 0; p < 16; ++p) {
        tm_scanall<<<1, 512, 0, stream>>>(P, G, CU, p);
        if (p < 15) {
            tm_wupd<<<(DD * DD) / 256, 256, 0, stream>>>(A, CU, W, WS, Wb, outW, p, p + 1, 0);
            tm_P<<<32, 256, 0, stream>>>(A, W, P, p + 1);
        }
    }
    tm_wupd<<<(DD * DD) / 256, 256, 0, stream>>>(A, CU, W, WS, Wb, outW, 15, -1, 1);

    tm_score<<<16 * 128, 256, 0, stream>>>(x, A, S);
    tm_fused<<<16 * 256, 256, 0, stream>>>(x, WS, S, CU, gw, gb, out);
}

// Round 8
// 17649.239 us; speedup vs baseline: 1.1924x; 1.1662x over previous
//
#include <hip/hip_runtime.h>
#include <math.h>

#define BB 8
#define TT 4096
#define DD 512
constexpr float LRF = 0.01f;

// ---------------- workspace layout (floats) ----------------
// A  : [4096][512]        mean of x over batch
// CU : [4096][512]        c_s * u_s
// G  : [16][256][256]     per-superchunk Gram of A
// P  : [256][512]         A_sc - A_sc @ W(p)^T   (reused per superchunk)
// W  : [512][512]         running W_base + W_c
// WS : [16][512][512]     W snapshots at t = 256*p
// S  : [16][2048][256]    attention scores
#define OFF_A  0
#define OFF_CU 2097152
#define OFF_G  4194304
#define OFF_P  5242880
#define OFF_W  5406720
#define OFF_WS 5668864
#define OFF_S  9863168

__global__ void tm_mean(const float* __restrict__ x, float* __restrict__ a) {
    int idx = blockIdx.x * 256 + threadIdx.x;   // t*D + d
    float s = 0.f;
#pragma unroll
    for (int b = 0; b < BB; ++b) s += x[b * (TT * DD) + idx];
    a[idx] = s * 0.125f;
}

__global__ void tm_init(const float* __restrict__ wb, const float* __restrict__ wc,
                        float* __restrict__ W, float* __restrict__ Wsnap) {
    int idx = blockIdx.x * 256 + threadIdx.x;
    float v = wb[idx] + wc[idx];
    W[idx] = v;
    Wsnap[idx] = v;   // snapshot p=0 (t=0)
}

// full Gram per superchunk: G[p][s][t] = a_{p*256+s} . a_{p*256+t}
__global__ __launch_bounds__(256) void tm_gram(const float* __restrict__ a, float* __restrict__ G) {
    __shared__ float sl[64 * 65];
    __shared__ float tl[64 * 65];
    int bid = blockIdx.x;
    int p = bid >> 4, ts = (bid >> 2) & 3, tt = bid & 3;
    int tid = threadIdx.x;
    int c0 = (tid & 15) * 4, r0 = (tid >> 4) * 4;
    float acc[4][4] = {};
    for (int kt = 0; kt < 8; ++kt) {
        if (kt) __syncthreads();
        for (int l = tid; l < 64 * 16; l += 256) {
            int r = l >> 4, c4 = (l & 15) * 4;
            float4 v = *(const float4*)&a[(p * 256 + ts * 64 + r) * DD + kt * 64 + c4];
            sl[r * 65 + c4] = v.x; sl[r * 65 + c4 + 1] = v.y;
            sl[r * 65 + c4 + 2] = v.z; sl[r * 65 + c4 + 3] = v.w;
            float4 u = *(const float4*)&a[(p * 256 + tt * 64 + r) * DD + kt * 64 + c4];
            tl[r * 65 + c4] = u.x; tl[r * 65 + c4 + 1] = u.y;
            tl[r * 65 + c4 + 2] = u.z; tl[r * 65 + c4 + 3] = u.w;
        }
        __syncthreads();
        for (int kk = 0; kk < 64; ++kk) {
            float as[4], at[4];
#pragma unroll
            for (int q = 0; q < 4; ++q) { as[q] = sl[(r0 + q) * 65 + kk]; at[q] = tl[(c0 + q) * 65 + kk]; }
#pragma unroll
            for (int q = 0; q < 4; ++q)
#pragma unroll
                for (int w2 = 0; w2 < 4; ++w2) acc[q][w2] += as[q] * at[w2];
        }
    }
#pragma unroll
    for (int q = 0; q < 4; ++q) {
        float4 v = make_float4(acc[q][0], acc[q][1], acc[q][2], acc[q][3]);
        *(float4*)&G[p * 65536 + (ts * 64 + r0 + q) * 256 + tt * 64 + c0] = v;
    }
}

// P[t][i] = a[p*256+t][i] - sum_j W[i][j] a[p*256+t][j];  grid 32 (bt 0..3, bi 0..7)
__global__ __launch_bounds__(256) void tm_P(const float* __restrict__ a, const float* __restrict__ W,
                                            float* __restrict__ P, int p) {
    __shared__ float al[64 * 65];
    __shared__ float wl[64 * 65];
    int bid = blockIdx.x;
    int bt = bid & 3, bi = bid >> 2;
    int tid = threadIdx.x;
    int c0 = (tid & 15) * 4, r0 = (tid >> 4) * 4;
    float acc[4][4] = {};
    for (int kt = 0; kt < 8; ++kt) {
        if (kt) __syncthreads();
        for (int l = tid; l < 64 * 16; l += 256) {
            int r = l >> 4, c4 = (l & 15) * 4;
            float4 v = *(const float4*)&a[(p * 256 + bt * 64 + r) * DD + kt * 64 + c4];
            al[r * 65 + c4] = v.x; al[r * 65 + c4 + 1] = v.y;
            al[r * 65 + c4 + 2] = v.z; al[r * 65 + c4 + 3] = v.w;
            float4 u = *(const float4*)&W[(bi * 64 + r) * DD + kt * 64 + c4];
            wl[r * 65 + c4] = u.x; wl[r * 65 + c4 + 1] = u.y;
            wl[r * 65 + c4 + 2] = u.z; wl[r * 65 + c4 + 3] = u.w;
        }
        __syncthreads();
        for (int kk = 0; kk < 64; ++kk) {
            float af[4], bf[4];
#pragma unroll
            for (int q = 0; q < 4; ++q) { af[q] = al[(r0 + q) * 65 + kk]; bf[q] = wl[(c0 + q) * 65 + kk]; }
#pragma unroll
            for (int q = 0; q < 4; ++q)
#pragma unroll
                for (int w2 = 0; w2 < 4; ++w2) acc[q][w2] += af[q] * bf[w2];
        }
    }
#pragma unroll
    for (int q = 0; q < 4; ++q) {
        float4 av = *(const float4*)&a[(p * 256 + bt * 64 + r0 + q) * DD + bi * 64 + c0];
        float4 v = make_float4(av.x - acc[q][0], av.y - acc[q][1],
                               av.z - acc[q][2], av.w - acc[q][3]);
        *(float4*)&P[(bt * 64 + r0 + q) * DD + bi * 64 + c0] = v;
    }
}

// =====================================================================
// scanall v3: ALL per-chunk state in LDS so every loop stays ROLLED and
// registers stay tiny (R6/R7 post-mortem: acc[64]-in-regs forced a 64-step
// full unroll the compiler refused -> scratch spill, 5.2MB writeback).
//   u : [64][512] LDS (128 KB)    H : [64][65] LDS (16.3 KB)
//   G : read from GLOBAL with wave-uniform/coalesced addresses (L1-hot 16KB)
// Per chunk j: corr (regs, 2x32-row passes) -> u; Gram H=u.u^T (4x2 tile,
// staggered d); scan 64 steps with v2's H rank-1 recursion, split into
// read-phase / barrier / write-phase (also fixes v2's latent H row-t race).
// CU global RAW (corr reads chunks this thread wrote) is same-thread,
// same-address -> program order suffices (R4/R5-proven pattern).
// =====================================================================
__global__ __launch_bounds__(512) void tm_scanall(const float* __restrict__ P4,
                                                  const float* __restrict__ G,
                                                  float* __restrict__ CU, int p) {
    __shared__ float u_l[64 * 512];   // 131072 B
    __shared__ float Hs[64 * 65];     // 16640 B   (total 147712 <= 160K)
    const int tid = threadIdx.x;                    // thread = dim d
    const int c0 = (tid & 31) * 2, r0 = (tid >> 5) * 4;   // 4x2 H tile
    const float* Gp = G + p * 65536;

    for (int j = 0; j < 4; ++j) {
        // ---- corr in registers (2 passes x 32 rows), store to u_l ----
        for (int pass = 0; pass < 2; ++pass) {
            const int rows = pass * 32;
            float b[32];
#pragma unroll
            for (int q = 0; q < 32; ++q)
                b[q] = P4[(j * 64 + rows + q) * DD + tid];
            for (int kb = 0; kb < j; ++kb) {
                const float* cub = CU + (p * 256 + kb * 64) * DD;
                for (int s = 0; s < 64; ++s) {
                    float cw = LRF * cub[s * DD + tid];
                    const float* gs = Gp + (kb * 64 + s) * 256 + j * 64 + rows;  // uniform
#pragma unroll
                    for (int q = 0; q < 32; ++q) b[q] -= gs[q] * cw;
                }
            }
#pragma unroll
            for (int q = 0; q < 32; ++q)
                u_l[(rows + q) * DD + tid] = b[q];
        }
        __syncthreads();

        // ---- Gram: Hs[a][b] = sum_d u_a[d]*u_b[d]; staggered d (bank-spread) ----
        {
            float h00 = 0, h01 = 0, h10 = 0, h11 = 0, h20 = 0, h21 = 0, h30 = 0, h31 = 0;
            for (int i = 0; i < 512; ++i) {
                int dd = (tid + i) & 511;
                float a0 = u_l[(r0 + 0) * DD + dd];
                float a1 = u_l[(r0 + 1) * DD + dd];
                float a2 = u_l[(r0 + 2) * DD + dd];
                float a3 = u_l[(r0 + 3) * DD + dd];
                float e0 = u_l[(c0 + 0) * DD + dd];
                float e1 = u_l[(c0 + 1) * DD + dd];
                h00 += a0 * e0; h01 += a0 * e1; h10 += a1 * e0; h11 += a1 * e1;
                h20 += a2 * e0; h21 += a2 * e1; h30 += a3 * e0; h31 += a3 * e1;
            }
            Hs[(r0 + 0) * 65 + c0] = h00; Hs[(r0 + 0) * 65 + c0 + 1] = h01;
            Hs[(r0 + 1) * 65 + c0] = h10; Hs[(r0 + 1) * 65 + c0 + 1] = h11;
            Hs[(r0 + 2) * 65 + c0] = h20; Hs[(r0 + 2) * 65 + c0 + 1] = h21;
            Hs[(r0 + 3) * 65 + c0] = h30; Hs[(r0 + 3) * 65 + c0 + 1] = h31;
        }
        __syncthreads();

        // ---- scan: 64 steps; read-phase / barrier / write-phase ----
        float* cup = CU + (p * 256 + j * 64) * DD;
        const float* gdiag = Gp + (j * 64) * 256 + j * 64;   // gdiag[t*256 + t0]
        for (int t = 0; t < 64; ++t) {
            const float* gt = gdiag + t * 256;
            // read phase (state from end of step t-1)
            float htt = Hs[t * 65 + t];
            float n2 = htt * gt[t];                              // ||u||^2 * ||a||^2
            float cs = (n2 > 0.25f) ? 0.5f * rsqrtf(n2) : 1.0f;  // min(1, CLIP/n)
            float alr = LRF * cs;
            float ut = u_l[t * DD + tid];
            float hA0 = Hs[(r0 + 0) * 65 + t], hA1 = Hs[(r0 + 1) * 65 + t];
            float hA2 = Hs[(r0 + 2) * 65 + t], hA3 = Hs[(r0 + 3) * 65 + t];
            float hB0 = Hs[t * 65 + c0], hB1 = Hs[t * 65 + c0 + 1];
            float aA0 = (r0 + 0 > t) ? alr * gt[r0 + 0] : 0.f;
            float aA1 = (r0 + 1 > t) ? alr * gt[r0 + 1] : 0.f;
            float aA2 = (r0 + 2 > t) ? alr * gt[r0 + 2] : 0.f;
            float aA3 = (r0 + 3 > t) ? alr * gt[r0 + 3] : 0.f;
            float aB0 = (c0 + 0 > t) ? alr * gt[c0 + 0] : 0.f;
            float aB1 = (c0 + 1 > t) ? alr * gt[c0 + 1] : 0.f;
            __syncthreads();
            // write phase
            cup[t * DD + tid] = cs * ut;
            float w0 = alr * ut;
            for (int t0 = t + 1; t0 < 64; ++t0)
                u_l[t0 * DD + tid] -= gt[t0] * w0;
            Hs[(r0 + 0) * 65 + c0]     += -aB0 * hA0 - aA0 * hB0 + aA0 * aB0 * htt;
            Hs[(r0 + 0) * 65 + c0 + 1] += -aB1 * hA0 - aA0 * hB1 + aA0 * aB1 * htt;
            Hs[(r0 + 1) * 65 + c0]     += -aB0 * hA1 - aA1 * hB0 + aA1 * aB0 * htt;
            Hs[(r0 + 1) * 65 + c0 + 1] += -aB1 * hA1 - aA1 * hB1 + aA1 * aB1 * htt;
            Hs[(r0 + 2) * 65 + c0]     += -aB0 * hA2 - aA2 * hB0 + aA2 * aB0 * htt;
            Hs[(r0 + 2) * 65 + c0 + 1] += -aB1 * hA2 - aA2 * hB1 + aA2 * aB1 * htt;
            Hs[(r0 + 3) * 65 + c0]     += -aB0 * hA3 - aA3 * hB0 + aA3 * aB0 * htt;
            Hs[(r0 + 3) * 65 + c0 + 1] += -aB1 * hA3 - aA3 * hB1 + aA3 * aB1 * htt;
            __syncthreads();
        }
    }
}

// W += LR * sum_{r in sc p} cu_r (x) a_r  (rank-256); optional snapshot / final output
__global__ void tm_wupd(const float* __restrict__ a, const float* __restrict__ cu,
                        float* __restrict__ W, float* __restrict__ Wsnap,
                        const float* __restrict__ wb, float* __restrict__ outW,
                        int p, int snap_p, int is_final) {
    int idx = blockIdx.x * 256 + threadIdx.x;
    int i = idx >> 9, jj = idx & 511;
    const float* cb = cu + p * 256 * DD + i;
    const float* ab = a + p * 256 * DD + jj;
    float s = 0.f;
#pragma unroll 8
    for (int r = 0; r < 256; ++r) s += cb[r * DD] * ab[r * DD];
    float w = W[idx] + LRF * s;
    W[idx] = w;
    if (snap_p >= 0) Wsnap[snap_p * DD * DD + idx] = w;
    if (is_final) outW[idx] = w - wb[idx];
}

// ---------------- phase 3 (parallel output) ----------------

// S[p][rloc][s] = x[row] . a[p*256+s]
__global__ __launch_bounds__(256) void tm_score(const float* __restrict__ x, const float* __restrict__ a,
                                                float* __restrict__ S) {
    __shared__ float al[64 * 65];
    __shared__ float bl[64 * 65];
    int bid = blockIdx.x;
    int st = bid & 3, rt = (bid >> 2) & 31, p = bid >> 7;
    int tid = threadIdx.x;
    int c0 = (tid & 15) * 4, r0 = (tid >> 4) * 4;
    float acc[4][4] = {};
    for (int kt = 0; kt < 8; ++kt) {
        if (kt) __syncthreads();
        for (int l = tid; l < 64 * 16; l += 256) {
            int r = l >> 4, c4 = (l & 15) * 4;
            int rloc = rt * 64 + r;
            int grow = ((rloc >> 8) * TT) + p * 256 + (rloc & 255);
            float4 v = *(const float4*)&x[grow * DD + kt * 64 + c4];
            al[r * 65 + c4] = v.x; al[r * 65 + c4 + 1] = v.y;
            al[r * 65 + c4 + 2] = v.z; al[r * 65 + c4 + 3] = v.w;
            float4 u = *(const float4*)&a[(p * 256 + st * 64 + r) * DD + kt * 64 + c4];
            bl[r * 65 + c4] = u.x; bl[r * 65 + c4 + 1] = u.y;
            bl[r * 65 + c4 + 2] = u.z; bl[r * 65 + c4 + 3] = u.w;
        }
        __syncthreads();
        for (int kk = 0; kk < 64; ++kk) {
            float af[4], bf[4];
#pragma unroll
            for (int q = 0; q < 4; ++q) { af[q] = al[(r0 + q) * 65 + kk]; bf[q] = bl[(c0 + q) * 65 + kk]; }
#pragma unroll
            for (int q = 0; q < 4; ++q)
#pragma unroll
                for (int w2 = 0; w2 < 4; ++w2) acc[q][w2] += af[q] * bf[w2];
        }
    }
#pragma unroll
    for (int q = 0; q < 4; ++q) {
        int rloc = rt * 64 + r0 + q;
        float4 v = make_float4(acc[q][0], acc[q][1], acc[q][2], acc[q][3]);
        *(float4*)&S[(p * 2048 + rloc) * 256 + st * 64 + c0] = v;
    }
}

// FUSED mem+apply+gate per 64x64 out tile:
// out[row][i] = sigmoid(x.gw[i]+gb[i]) * ( x.WS[p][i] + LR*sum_{s<tloc} S*cu )
__global__ __launch_bounds__(256) void tm_fused(const float* __restrict__ x, const float* __restrict__ Wsnap,
                                                const float* __restrict__ S, const float* __restrict__ cu,
                                                const float* __restrict__ gw, const float* __restrict__ gb,
                                                float* __restrict__ out) {
    __shared__ float al[64 * 65];
    __shared__ float bl[64 * 65];
    int bid = blockIdx.x;
    int p = bid >> 8, rem = bid & 255, rt = rem >> 3, it = rem & 7;
    int tid = threadIdx.x;
    int c0 = (tid & 15) * 4, r0 = (tid >> 4) * 4;
    int growbase = (rt >> 2) * TT + p * 256 + (rt & 3) * 64;
    const float* xb = x + growbase * DD;
    const float* Wp = Wsnap + p * DD * DD + it * 64 * DD;
    const float* gwp = gw + it * 64 * DD;

    float accM[4][4] = {};
    float accG[4][4] = {};
    float accA[4][4] = {};

    for (int kt = 0; kt < 8; ++kt) {
        if (kt) __syncthreads();
        for (int l = tid; l < 64 * 16; l += 256) {
            int r = l >> 4, c4 = (l & 15) * 4;
            float4 v = *(const float4*)&xb[r * DD + kt * 64 + c4];
            al[r * 65 + c4] = v.x; al[r * 65 + c4 + 1] = v.y;
            al[r * 65 + c4 + 2] = v.z; al[r * 65 + c4 + 3] = v.w;
            float4 u = *(const float4*)&Wp[r * DD + kt * 64 + c4];
            bl[r * 65 + c4] = u.x; bl[r * 65 + c4 + 1] = u.y;
            bl[r * 65 + c4 + 2] = u.z; bl[r * 65 + c4 + 3] = u.w;
        }
        __syncthreads();
        for (int kk = 0; kk < 64; ++kk) {
            float af[4], bf[4];
#pragma unroll
            for (int q = 0; q < 4; ++q) { af[q] = al[(r0 + q) * 65 + kk]; bf[q] = bl[(c0 + q) * 65 + kk]; }
#pragma unroll
            for (int q = 0; q < 4; ++q)
#pragma unroll
                for (int w2 = 0; w2 < 4; ++w2) accM[q][w2] += af[q] * bf[w2];
        }
        __syncthreads();
        for (int l = tid; l < 64 * 16; l += 256) {
            int r = l >> 4, c4 = (l & 15) * 4;
            float4 u = *(const float4*)&gwp[r * DD + kt * 64 + c4];
            bl[r * 65 + c4] = u.x; bl[r * 65 + c4 + 1] = u.y;
            bl[r * 65 + c4 + 2] = u.z; bl[r * 65 + c4 + 3] = u.w;
        }
        __syncthreads();
        for (int kk = 0; kk < 64; ++kk) {
            float af[4], bf[4];
#pragma unroll
            for (int q = 0; q < 4; ++q) { af[q] = al[(r0 + q) * 65 + kk]; bf[q] = bl[(c0 + q) * 65 + kk]; }
#pragma unroll
            for (int q = 0; q < 4; ++q)
#pragma unroll
                for (int w2 = 0; w2 < 4; ++w2) accG[q][w2] += af[q] * bf[w2];
        }
    }

    for (int kt = 0; kt < 4; ++kt) {
        __syncthreads();
        for (int l = tid; l < 64 * 16; l += 256) {
            int r = l >> 4, c4 = (l & 15) * 4;
            int rloc = rt * 64 + r;
            int tq = rloc & 255;
            float4 v = *(const float4*)&S[(p * 2048 + rloc) * 256 + kt * 64 + c4];
            int sb = kt * 64 + c4;
            al[r * 65 + c4]     = (sb + 0 < tq) ? v.x : 0.f;
            al[r * 65 + c4 + 1] = (sb + 1 < tq) ? v.y : 0.f;
            al[r * 65 + c4 + 2] = (sb + 2 < tq) ? v.z : 0.f;
            al[r * 65 + c4 + 3] = (sb + 3 < tq) ? v.w : 0.f;
            float4 u = *(const float4*)&cu[(p * 256 + kt * 64 + r) * DD + it * 64 + c4];
            bl[r * 65 + c4] = u.x; bl[r * 65 + c4 + 1] = u.y;
            bl[r * 65 + c4 + 2] = u.z; bl[r * 65 + c4 + 3] = u.w;
        }
        __syncthreads();
        for (int kk = 0; kk < 64; ++kk) {
            float af[4], bf[4];
#pragma unroll
            for (int q = 0; q < 4; ++q) { af[q] = al[(r0 + q) * 65 + kk]; bf[q] = bl[kk * 65 + c0 + q]; }
#pragma unroll
            for (int q = 0; q < 4; ++q)
#pragma unroll
                for (int w2 = 0; w2 < 4; ++w2) accA[q][w2] += af[q] * bf[w2];
        }
    }

#pragma unroll
    for (int q = 0; q < 4; ++q) {
        float4 v;
        float z0 = accG[q][0] + gb[it * 64 + c0 + 0];
        float z1 = accG[q][1] + gb[it * 64 + c0 + 1];
        float z2 = accG[q][2] + gb[it * 64 + c0 + 2];
        float z3 = accG[q][3] + gb[it * 64 + c0 + 3];
        v.x = (accM[q][0] + LRF * accA[q][0]) / (1.f + expf(-z0));
        v.y = (accM[q][1] + LRF * accA[q][1]) / (1.f + expf(-z1));
        v.z = (accM[q][2] + LRF * accA[q][2]) / (1.f + expf(-z2));
        v.w = (accM[q][3] + LRF * accA[q][3]) / (1.f + expf(-z3));
        *(float4*)&out[(growbase + r0 + q) * DD + it * 64 + c0] = v;
    }
}

extern "C" void kernel_launch(void* const* d_in, const int* in_sizes, int n_in,
                              void* d_out, int out_size, void* d_ws, size_t ws_size,
                              hipStream_t stream) {
    const float* x   = (const float*)d_in[0];
    const float* Wc0 = (const float*)d_in[1];
    const float* Wb  = (const float*)d_in[2];
    const float* gw  = (const float*)d_in[3];
    const float* gb  = (const float*)d_in[4];
    float* out  = (float*)d_out;
    float* outW = out + BB * TT * DD;

    float* ws = (float*)d_ws;
    float* A  = ws + OFF_A;
    float* CU = ws + OFF_CU;
    float* G  = ws + OFF_G;
    float* P  = ws + OFF_P;
    float* W  = ws + OFF_W;
    float* WS = ws + OFF_WS;
    float* S  = ws + OFF_S;

    tm_mean<<<(TT * DD) / 256, 256, 0, stream>>>(x, A);
    tm_init<<<(DD * DD) / 256, 256, 0, stream>>>(Wb, Wc0, W, WS);
    tm_gram<<<256, 256, 0, stream>>>(A, G);
    tm_P<<<32, 256, 0, stream>>>(A, W, P, 0);

    for (int p = 0; p < 16; ++p) {
        tm_scanall<<<1, 512, 0, stream>>>(P, G, CU, p);
        if (p < 15) {
            tm_wupd<<<(DD * DD) / 256, 256, 0, stream>>>(A, CU, W, WS, Wb, outW, p, p + 1, 0);
            tm_P<<<32, 256, 0, stream>>>(A, W, P, p + 1);
        }
    }
    tm_wupd<<<(DD * DD) / 256, 256, 0, stream>>>(A, CU, W, WS, Wb, outW, 15, -1, 1);

    tm_score<<<16 * 128, 256, 0, stream>>>(x, A, S);
    tm_fused<<<16 * 256, 256, 0, stream>>>(x, WS, S, CU, gw, gb, out);
}